// Round 2
// baseline (114.295 us; speedup 1.0000x reference)
//
#include <hip/hip_runtime.h>
#include <hip/hip_bf16.h>
#include <cstdint>

#define IDIM 1024
#define HID  256

typedef __attribute__((ext_vector_type(4))) float f32x4;
typedef __attribute__((ext_vector_type(8))) short short8;
typedef __attribute__((ext_vector_type(4))) unsigned int u32x4;

__device__ __forceinline__ unsigned pk_bf16(float a, float b) {
  __hip_bfloat162 h = __float22bfloat162_rn(make_float2(a, b));
  unsigned r; __builtin_memcpy(&r, &h, 4); return r;
}

#define LGKM_BARRIER() do { \
  asm volatile("s_waitcnt lgkmcnt(0)" ::: "memory"); \
  __builtin_amdgcn_s_barrier(); } while (0)

// ---------------------------------------------------------------------------
// Prep: W1bT[n][k] = bf16(ln_w[k] * W1[k][n])   (transposed, row-scaled)
//       t2[n]  = sum_k ln_w[k]*W1[k][n]
//       tc1[n] = sum_k ln_b[k]*W1[k][n] + b1[n]
// Grid 16 blocks x 256 thr. Thread (kg=t>>4, ni=t&15) owns column n0+ni,
// k-range [kg*64, kg*64+64): W1 reads are 64-B coalesced per 16-lane group,
// w1bt writes are 128 B contiguous per thread. No transpose LDS needed.
// ---------------------------------------------------------------------------
__global__ __launch_bounds__(256)
void prep_kernel(const float* __restrict__ W1, const float* __restrict__ lnw,
                 const float* __restrict__ lnb, const float* __restrict__ b1,
                 unsigned short* __restrict__ w1bt, float* __restrict__ t2g,
                 float* __restrict__ tc1g) {
  const int t  = threadIdx.x;
  const int ni = t & 15, kg = t >> 4;
  const int n  = blockIdx.x * 16 + ni;
  const int k0 = kg * 64;
  float s1 = 0.f, s2 = 0.f;
  unsigned pk[32];
#pragma unroll
  for (int j = 0; j < 64; j += 2) {
    const int k = k0 + j;
    const float v0 = W1[(size_t)k * HID + n];
    const float v1 = W1[(size_t)(k + 1) * HID + n];
    const float sc0 = lnw[k] * v0, sc1 = lnw[k + 1] * v1;
    s2 += sc0 + sc1;
    s1 = fmaf(lnb[k], v0, fmaf(lnb[k + 1], v1, s1));
    pk[j >> 1] = pk_bf16(sc0, sc1);
  }
  u32x4* dst = reinterpret_cast<u32x4*>(w1bt + (size_t)n * IDIM + k0);
#pragma unroll
  for (int i = 0; i < 8; ++i) {
    const u32x4 v = {pk[i * 4], pk[i * 4 + 1], pk[i * 4 + 2], pk[i * 4 + 3]};
    dst[i] = v;
  }
  __shared__ float red[2][16][17];
  red[0][kg][ni] = s1; red[1][kg][ni] = s2;
  __syncthreads();
  if (kg == 0) {
    float a = 0.f, b = 0.f;
#pragma unroll
    for (int i = 0; i < 16; ++i) { a += red[0][i][ni]; b += red[1][i][ni]; }
    tc1g[n] = a + b1[n];
    t2g[n]  = b;
  }
}

// ---------------------------------------------------------------------------
// Main fused kernel. Block = 64 rows x 256 cols; wave w owns cols w*64..+64.
// A (embedding, HBM stream): reg-staged 2-deep -> stats -> bf16 -> swizzled
//   LDS dbuf [2][64][64] (16 KiB). Only lgkmcnt(0)+s_barrier per step — A
//   global loads stay in flight across barriers.
// B (w1bt, L2-resident 512 KiB): per-fragment direct global->VGPR loads, no
//   LDS, drained by MFMA data deps within the step.
// z = rs*acc - (mu*rs)*t2 + tc1; h = gelu(z); out = h@W2 + b2 (shfl-reduced).
// ---------------------------------------------------------------------------
__global__ __launch_bounds__(256, 2)
void head_kernel(const float* __restrict__ emb,
                 const unsigned short* __restrict__ w1bt,
                 const float* __restrict__ t2g, const float* __restrict__ tc1g,
                 const float* __restrict__ w2g, const float* __restrict__ b2g,
                 float* __restrict__ out) {
  __shared__ __align__(16) char smem[16384];  // A dbuf [2][64 rows][64 k] bf16
  float* const stats = reinterpret_cast<float*>(smem);        // overlay
  float* const pout  = reinterpret_cast<float*>(smem + 512);  // overlay

  const int t  = threadIdx.x;
  const int l  = t & 63;
  const int w  = t >> 6;
  const int lr = l & 15;
  const int lk = l >> 4;
  const int m0 = blockIdx.x * 64;

  // A staging: thread owns row ar, 16 fp32 (64 B) per step
  const int ar  = t >> 2;
  const int acb = (t & 3) * 2;
  const float* const Ag = emb + (size_t)(m0 + ar) * IDIM + (t & 3) * 16;
  char* const aw0 = smem + ar * 128 + ((acb ^ (ar & 7)) * 16);
  char* const aw1 = smem + ar * 128 + (((acb + 1) ^ (ar & 7)) * 16);

  // B fragment base: row (w*64 + lr), k-lane offset lk*8
  const unsigned short* const bp = w1bt + (size_t)(w * 64 + lr) * IDIM + lk * 8;

  f32x4 acc[4][4];
#pragma unroll
  for (int i = 0; i < 4; ++i)
#pragma unroll
    for (int j = 0; j < 4; ++j) acc[i][j] = f32x4{0.f, 0.f, 0.f, 0.f};

  float sum = 0.f, ssq = 0.f;

  auto issueA = [&](int s, f32x4* S) {
    const f32x4* p = reinterpret_cast<const f32x4*>(Ag + (size_t)s * 64);
    S[0] = p[0]; S[1] = p[1]; S[2] = p[2]; S[3] = p[3];
  };
  auto writeA = [&](f32x4* S, int buf) {
#pragma unroll
    for (int q = 0; q < 4; ++q)
#pragma unroll
      for (int j = 0; j < 4; ++j) {
        sum += S[q][j];
        ssq = fmaf(S[q][j], S[q][j], ssq);
      }
    const u32x4 c0 = {pk_bf16(S[0][0], S[0][1]), pk_bf16(S[0][2], S[0][3]),
                      pk_bf16(S[1][0], S[1][1]), pk_bf16(S[1][2], S[1][3])};
    const u32x4 c1 = {pk_bf16(S[2][0], S[2][1]), pk_bf16(S[2][2], S[2][3]),
                      pk_bf16(S[3][0], S[3][1]), pk_bf16(S[3][2], S[3][3])};
    *reinterpret_cast<u32x4*>(aw0 + buf * 8192) = c0;
    *reinterpret_cast<u32x4*>(aw1 + buf * 8192) = c1;
  };
  auto compute = [&](int s, int buf) {
    const char* A = smem + buf * 8192;
    const unsigned short* bs = bp + s * 64;
#pragma unroll
    for (int kk = 0; kk < 2; ++kk) {
      short8 av[4], bv[4];
      const int pc = ((kk * 4 + lk) ^ (lr & 7)) * 16;
#pragma unroll
      for (int ni = 0; ni < 4; ++ni)
        bv[ni] = *reinterpret_cast<const short8*>(bs + ni * 16 * IDIM + kk * 32);
#pragma unroll
      for (int mi = 0; mi < 4; ++mi)
        av[mi] = *reinterpret_cast<const short8*>(A + (mi * 16 + lr) * 128 + pc);
#pragma unroll
      for (int mi = 0; mi < 4; ++mi)
#pragma unroll
        for (int ni = 0; ni < 4; ++ni)
          acc[mi][ni] = __builtin_amdgcn_mfma_f32_16x16x32_bf16(av[mi], bv[ni],
                                                                acc[mi][ni], 0, 0, 0);
    }
  };

  f32x4 SA[4], SB[4];
  // prologue: A(0) -> buf0 (stalls once on first HBM load), A(1) in flight
  issueA(0, SA);
  writeA(SA, 0);
  issueA(1, SB);
  LGKM_BARRIER();

  for (int s = 0; s < 16; s += 2) {
    if (s + 2 < 16) issueA(s + 2, SA);
    compute(s, 0);
    writeA(SB, 1);  // A(s+1) -> buf1 (loads completed ~1 full iter ago)
    LGKM_BARRIER();
    if (s + 3 < 16) issueA(s + 3, SB);
    compute(s + 1, 1);
    if (s + 2 < 16) writeA(SA, 0);
    LGKM_BARRIER();
  }

  // row stats: reduce over the 4 threads sharing a row, publish to LDS overlay
  sum += __shfl_xor(sum, 1); sum += __shfl_xor(sum, 2);
  ssq += __shfl_xor(ssq, 1); ssq += __shfl_xor(ssq, 2);
  if ((t & 3) == 0) {
    const float mu  = sum * (1.f / 1024.f);
    const float var = ssq * (1.f / 1024.f) - mu * mu;
    const float rs  = rsqrtf(var + 1e-5f);
    stats[ar * 2]     = mu * rs;
    stats[ar * 2 + 1] = rs;
  }
  __syncthreads();

  // epilogue: folded-LN affine -> exact GELU -> tiny second GEMM (256 -> 2)
  float po0[16], po1[16];
#pragma unroll
  for (int i = 0; i < 16; ++i) { po0[i] = 0.f; po1[i] = 0.f; }
#pragma unroll
  for (int ni = 0; ni < 4; ++ni) {
    const int n = w * 64 + ni * 16 + lr;
    const float t2n = t2g[n];
    const float tcn = tc1g[n];
    const float w20 = w2g[n * 2];
    const float w21 = w2g[n * 2 + 1];
#pragma unroll
    for (int mi = 0; mi < 4; ++mi) {
#pragma unroll
      for (int j = 0; j < 4; ++j) {
        const int r = mi * 16 + lk * 4 + j;
        const float mrs = stats[r * 2];
        const float rs  = stats[r * 2 + 1];
        const float z  = fmaf(rs, acc[mi][ni][j], fmaf(-mrs, t2n, tcn));
        const float hh = 0.5f * z * (1.f + erff(z * 0.70710678118654752f));
        po0[mi * 4 + j] = fmaf(hh, w20, po0[mi * 4 + j]);
        po1[mi * 4 + j] = fmaf(hh, w21, po1[mi * 4 + j]);
      }
    }
  }
#pragma unroll
  for (int i = 0; i < 16; ++i) {
#pragma unroll
    for (int d = 1; d < 16; d <<= 1) {
      po0[i] += __shfl_xor(po0[i], d);
      po1[i] += __shfl_xor(po1[i], d);
    }
  }
  if (lr == 0) {
#pragma unroll
    for (int mi = 0; mi < 4; ++mi)
#pragma unroll
      for (int j = 0; j < 4; ++j) {
        const int r = mi * 16 + lk * 4 + j;
        pout[(w * 64 + r) * 2 + 0] = po0[mi * 4 + j];
        pout[(w * 64 + r) * 2 + 1] = po1[mi * 4 + j];
      }
  }
  __syncthreads();
  if (t < 128) {
    const int r = t >> 1, o = t & 1;
    const float v = pout[r * 2 + o] + pout[(64 + r) * 2 + o] +
                    pout[(128 + r) * 2 + o] + pout[(192 + r) * 2 + o];
    out[(size_t)(m0 + r) * 2 + o] = v + b2g[o];
  }
}

extern "C" void kernel_launch(void* const* d_in, const int* in_sizes, int n_in,
                              void* d_out, int out_size, void* d_ws, size_t ws_size,
                              hipStream_t stream) {
  const float* emb = (const float*)d_in[0];
  const float* lnw = (const float*)d_in[1];
  const float* lnb = (const float*)d_in[2];
  const float* W1  = (const float*)d_in[3];
  const float* b1  = (const float*)d_in[4];
  const float* W2  = (const float*)d_in[5];
  const float* b2  = (const float*)d_in[6];
  float* out = (float*)d_out;

  unsigned short* w1bt = (unsigned short*)d_ws;                       // 512 KiB
  float* t2g  = (float*)((char*)d_ws + 524288);                       // 1 KiB
  float* tc1g = (float*)((char*)d_ws + 524288 + 1024);                // 1 KiB

  prep_kernel<<<HID / 16, 256, 0, stream>>>(W1, lnw, lnb, b1, w1bt, t2g, tc1g);
  head_kernel<<<65536 / 64, 256, 0, stream>>>(emb, w1bt, t2g, tc1g, W2, b2, out);
}